// Round 5
// baseline (740.902 us; speedup 1.0000x reference)
//
#include <hip/hip_runtime.h>
#include <hip/hip_bf16.h>
#include <math.h>

typedef __bf16 bf16_t;
typedef __attribute__((ext_vector_type(8))) __bf16 bf16x8;
typedef __attribute__((ext_vector_type(4))) float f32x4;

constexpr int B_ = 2, S_ = 4096, D_ = 512;
constexpr int BS_ = B_ * S_;
constexpr int GRID_ = 512;                       // == 2 blocks/CU exactly
constexpr int NT_ = 256;
constexpr long QKV_E  = (long)BS_ * D_;          // 4 Mi elems
constexpr long W_E    = (long)D_ * D_;           // 256 Ki elems (2^18)
constexpr long CVT_UNITS = (QKV_E + 4 * W_E) / 4;    // 1,310,720
constexpr float SCALE_ = 0.044194173824159216f;      // 1/sqrt(512)

// Async global->LDS 16B copy. LDS dest must be wave-uniform base + lane*16.
__device__ __forceinline__ void load16_lds(const bf16_t* g, bf16_t* l) {
    __builtin_amdgcn_global_load_lds(
        (const __attribute__((address_space(1))) void*)g,
        (__attribute__((address_space(3))) void*)l, 16, 0, 0);
}

// ---------------------------------------------------------------------------
// Software grid barrier. Requires all GRID_ blocks co-resident
// (__launch_bounds__(256,2), 32KB LDS -> 2 blocks/CU * 256 CU = 512).
// Device-scope release/acquire handles cross-XCD L2 (wb/inv at agent scope).
// Bounded spin: a co-residency failure produces a wrong answer, not a hang.
// ---------------------------------------------------------------------------
__device__ __forceinline__ void gbar(unsigned* bar, int idx) {
    __syncthreads();                 // all waves done; vmcnt drained by barrier
    if (threadIdx.x == 0) {
        unsigned* c = bar + idx * 32;            // own 128B line per barrier
        __threadfence();                         // device-scope release (L2 wb)
        __hip_atomic_fetch_add(c, 1u, __ATOMIC_RELEASE, __HIP_MEMORY_SCOPE_AGENT);
        long guard = 0;
        while (__hip_atomic_load(c, __ATOMIC_ACQUIRE, __HIP_MEMORY_SCOPE_AGENT)
               < (unsigned)GRID_) {
            if (++guard > (1L << 21)) break;     // ~1s safety valve
            __builtin_amdgcn_s_sleep(8);
        }
        __threadfence();                         // acquire side (L2 inv)
    }
    __syncthreads();
}

// ---------------------------------------------------------------------------
// Streaming: fp32->bf16 of x + 4 weights into contiguous Xc|Wq|Wk|Wv|Wo.
// ---------------------------------------------------------------------------
__device__ __forceinline__ void dev_cvt(long u,
    const float* x, const float* Wq, const float* Wk, const float* Wv,
    const float* Wo, bf16_t* dst)
{
    const long i = u * 4;
    const float* src; long o;
    if (i < QKV_E) { src = x; o = i; }
    else {
        const long j = i - QKV_E;
        const int w = (int)(j >> 18);
        o = j & (W_E - 1);
        src = (w == 0) ? Wq : (w == 1) ? Wk : (w == 2) ? Wv : Wo;
    }
    const float4 v = *(const float4*)(src + o);
    bf16_t out[4] = {(bf16_t)v.x, (bf16_t)v.y, (bf16_t)v.z, (bf16_t)v.w};
    *(uint2*)(dst + i) = *(uint2*)out;
}

// ---------------------------------------------------------------------------
// 128x128 tile GEMM K-loop, BK=64. LDS [128 rows][64 cols] bf16 per matrix.
// Linear gload_lds dest; XOR swizzle on the GLOBAL source col-group and on
// the read address (both-sides, rule 21). b128 reads at structural minimum.
// ---------------------------------------------------------------------------
__device__ __forceinline__ void kloop64(
    const bf16_t* At, const bf16_t* Bt, long ldA, long ldB, int kSteps,
    bf16_t* As, bf16_t* Bs, int tid, int wr, int wc, int quad, int r16,
    f32x4 (&acc)[4][4])
{
    const int srow = tid >> 3;                        // 0..31
    const int cg = ((tid & 7) ^ (srow & 7)) * 8;      // pre-swizzled src col
    const bf16_t* gA = At + (long)srow * ldA + cg;
    const bf16_t* gB = Bt + (long)srow * ldB + cg;
    bf16_t* lA = As + tid * 8;
    bf16_t* lB = Bs + tid * 8;

    for (int s = 0; s < kSteps; s++) {
        const int k0 = s * 64;
#pragma unroll
        for (int rr = 0; rr < 4; rr++) {
            load16_lds(gA + (long)rr * 32 * ldA + k0, lA + rr * 2048);
            load16_lds(gB + (long)rr * 32 * ldB + k0, lB + rr * 2048);
        }
        __syncthreads();
#pragma unroll
        for (int kh = 0; kh < 2; kh++) {
            bf16x8 af[4], bfr[4];
#pragma unroll
            for (int i = 0; i < 4; i++) {
                const int row = wr * 64 + i * 16 + r16;
                af[i] = *(const bf16x8*)(As + row * 64 +
                        (((kh << 2) + quad) ^ (row & 7)) * 8);
            }
#pragma unroll
            for (int j = 0; j < 4; j++) {
                const int row = wc * 64 + j * 16 + r16;
                bfr[j] = *(const bf16x8*)(Bs + row * 64 +
                        (((kh << 2) + quad) ^ (row & 7)) * 8);
            }
#pragma unroll
            for (int i = 0; i < 4; i++)
#pragma unroll
                for (int j = 0; j < 4; j++)
                    acc[i][j] = __builtin_amdgcn_mfma_f32_16x16x32_bf16(
                        af[i], bfr[j], acc[i][j], 0, 0, 0);
        }
        __syncthreads();
    }
}

// ---------------------------------------------------------------------------
// QKV + direct-V^T projections (sel 2 swaps operands: C[d][s] = V^T).
// ---------------------------------------------------------------------------
__device__ __forceinline__ void dev_qkv_tile(int t,
    const bf16_t* Xc, const bf16_t* Wqc, const bf16_t* Wkc, const bf16_t* Wvc,
    const float* bq, const float* bk, const float* bv,
    bf16_t* Q, bf16_t* Kp, bf16_t* VT, char* smem, int tid)
{
    constexpr int K = 512;
    const int sel = t >> 8;          // 0:Q 1:K 2:VT
    const int tt  = t & 255;

    bf16_t* As = (bf16_t*)smem;
    bf16_t* Bs = As + 128 * 64;
    const int wave = tid >> 6, lane = tid & 63;
    const int quad = lane >> 4, r16 = lane & 15;
    const int wr = wave >> 1, wc = wave & 1;

    f32x4 acc[4][4] = {};

    if (sel < 2) {
        const int m0 = (tt >> 2) * 128;          // X row tile (8192)
        const int n0 = (tt & 3) * 128;           // out-feature tile (512)
        const bf16_t* Bw = sel ? Wkc : Wqc;
        const float* bias = sel ? bk : bq;
        bf16_t* C = sel ? Kp : Q;
        kloop64(Xc + (long)m0 * K, Bw + (long)n0 * K, K, K, K / 64,
                As, Bs, tid, wr, wc, quad, r16, acc);
#pragma unroll
        for (int i = 0; i < 4; i++)
#pragma unroll
            for (int j = 0; j < 4; j++) {
                const int gn = n0 + wc * 64 + j * 16 + r16;
                const float bval = bias[gn];
#pragma unroll
                for (int reg = 0; reg < 4; reg++) {
                    const int gm = m0 + wr * 64 + i * 16 + quad * 4 + reg;
                    C[(long)gm * 512 + gn] = (bf16_t)(acc[i][j][reg] + bval);
                }
            }
    } else {
        const int m0 = (tt & 3) * 128;           // d tile (512)
        const int n0 = (tt >> 2) * 128;          // X row tile (8192)
        kloop64(Wvc + (long)m0 * K, Xc + (long)n0 * K, K, K, K / 64,
                As, Bs, tid, wr, wc, quad, r16, acc);
#pragma unroll
        for (int i = 0; i < 4; i++)
#pragma unroll
            for (int j = 0; j < 4; j++) {
                const int gn = n0 + wc * 64 + j * 16 + r16;   // global s-index
                const int b = gn >> 12, q = gn & 4095;
#pragma unroll
                for (int reg = 0; reg < 4; reg++) {
                    const int gm = m0 + wr * 64 + i * 16 + quad * 4 + reg; // d
                    VT[(long)b * D_ * S_ + (long)gm * S_ + q] =
                        (bf16_t)(acc[i][j][reg] + bv[gm]);
                }
            }
    }
}

// ---------------------------------------------------------------------------
// Scores: SC[q][k] = keep ? exp(scale*(Q.K)) : 0 (bf16), rowsum atomics.
// fp32 mask read directly (no pack pass). wlds padded [16][68].
// ---------------------------------------------------------------------------
__device__ __forceinline__ void dev_scores_tile(int t,
    const bf16_t* Q, const bf16_t* Kp, const float* mask,
    bf16_t* SC, float* rowsum, char* smem, int tid)
{
    constexpr int S = S_, K = D_;
    const int x = t & 31;
    const int y = (t >> 5) & 31;
    const int b = t >> 10;
    const int m0 = y * 128, n0 = x * 128;

    bf16_t* As = (bf16_t*)smem;
    bf16_t* Bs = As + 128 * 64;
    const int wave = tid >> 6, lane = tid & 63;
    const int quad = lane >> 4, r16 = lane & 15;
    const int wr = wave >> 1, wc = wave & 1;

    f32x4 acc[4][4] = {};
    kloop64(Q + (long)b * S * K + (long)m0 * K,
            Kp + (long)b * S * K + (long)n0 * K, K, K, K / 64,
            As, Bs, tid, wr, wc, quad, r16, acc);

    float* wlds = (float*)smem + wave * 1088;   // 16 rows x 68 cols fp32 (pad)
    const int erow = lane >> 2;
    const int ecg  = lane & 3;
    const long mbase = (long)b * S * S;

#pragma unroll
    for (int i = 0; i < 4; i++) {
#pragma unroll
        for (int j = 0; j < 4; j++)
#pragma unroll
            for (int reg = 0; reg < 4; reg++)
                wlds[(quad * 4 + reg) * 68 + j * 16 + r16] = acc[i][j][reg];
        __syncthreads();

        float v[16];
#pragma unroll
        for (int c = 0; c < 4; c++) {
            const float4 tv = *(const float4*)(wlds + erow * 68 + ecg * 16 + c * 4);
            v[c * 4 + 0] = tv.x; v[c * 4 + 1] = tv.y;
            v[c * 4 + 2] = tv.z; v[c * 4 + 3] = tv.w;
        }

        const int gm = m0 + wr * 64 + i * 16 + erow;
        const int gn = n0 + wc * 64 + ecg * 16;

        const float* mp = mask + mbase + (long)gm * S + gn;
        float e[16];
#pragma unroll
        for (int c = 0; c < 4; c++) {
            const float4 mk = *(const float4*)(mp + c * 4);
            e[c * 4 + 0] = (mk.x > 0.95f) ? __expf(v[c * 4 + 0] * SCALE_) : 0.f;
            e[c * 4 + 1] = (mk.y > 0.95f) ? __expf(v[c * 4 + 1] * SCALE_) : 0.f;
            e[c * 4 + 2] = (mk.z > 0.95f) ? __expf(v[c * 4 + 2] * SCALE_) : 0.f;
            e[c * 4 + 3] = (mk.w > 0.95f) ? __expf(v[c * 4 + 3] * SCALE_) : 0.f;
        }

        bf16x8 o0, o1;
        float rsum = 0.f;
#pragma unroll
        for (int tt = 0; tt < 8; tt++) {
            rsum += e[tt] + e[tt + 8];
            o0[tt] = (bf16_t)e[tt];
            o1[tt] = (bf16_t)e[tt + 8];
        }
        bf16_t* cp = SC + mbase + (long)gm * S + gn;
        *(bf16x8*)cp       = o0;
        *(bf16x8*)(cp + 8) = o1;

        rsum += __shfl_xor(rsum, 1, 64);
        rsum += __shfl_xor(rsum, 2, 64);
        if (ecg == 0) atomicAdd(&rowsum[b * S + gm], rsum);
        __syncthreads();
    }
}

// ---------------------------------------------------------------------------
// PV split-K (KS=2), normalized bf16 partials [ks][b][d][q].
// ---------------------------------------------------------------------------
__device__ __forceinline__ void dev_pv_tile(int t,
    const bf16_t* VT, const bf16_t* SC, const float* rowsum,
    bf16_t* part, char* smem, int tid)
{
    constexpr int S = S_, D = D_;
    constexpr int KC = S / 2;                   // 2048
    const int x = t & 31;                       // q tile
    const int y = (t >> 5) & 3;                 // d tile
    const int z = t >> 7;                       // 0..3
    const int b = z >> 1, ks = z & 1;
    const int m0 = y * 128, n0 = x * 128;
    const int kbeg = ks * KC;

    bf16_t* As = (bf16_t*)smem;
    bf16_t* Bs = As + 128 * 64;
    const int wave = tid >> 6, lane = tid & 63;
    const int quad = lane >> 4, r16 = lane & 15;
    const int wr = wave >> 1, wc = wave & 1;

    f32x4 acc[4][4] = {};
    kloop64(VT + (long)b * D * S + (long)m0 * S + kbeg,
            SC + (long)b * S * S + (long)n0 * S + kbeg, S, S, KC / 64,
            As, Bs, tid, wr, wc, quad, r16, acc);

    const long obase = ((long)ks * B_ + b) * (long)D * S;
#pragma unroll
    for (int i = 0; i < 4; i++)
#pragma unroll
        for (int j = 0; j < 4; j++) {
            const int gn = n0 + wc * 64 + j * 16 + r16;
            const float inv = 1.f / rowsum[b * S + gn];
#pragma unroll
            for (int reg = 0; reg < 4; reg++) {
                const int gm = m0 + wr * 64 + i * 16 + quad * 4 + reg;
                part[obase + (long)gm * S + gn] = (bf16_t)(acc[i][j][reg] * inv);
            }
        }
}

// ---------------------------------------------------------------------------
// Out projection with INLINE partial reduction (A = part0 + part1 reg-staged,
// swizzled ds_write; B = Wo via gload_lds). fp32 out + bias.
// ---------------------------------------------------------------------------
__device__ __forceinline__ void dev_out_tile(int t,
    const bf16_t* part, const bf16_t* Woc, const float* bo, float* C,
    char* smem, int tid)
{
    constexpr int N = 512, K = 512;
    const int m0 = (t >> 2) * 128, n0 = (t & 3) * 128;

    bf16_t* As = (bf16_t*)smem;
    bf16_t* Bs = As + 128 * 64;
    const int wave = tid >> 6, lane = tid & 63;
    const int quad = lane >> 4, r16 = lane & 15;
    const int wr = wave >> 1, wc = wave & 1;

    const int srow = tid >> 3;
    const int cg = ((tid & 7) ^ (srow & 7)) * 8;
    const bf16_t* gA0 = part + (long)(m0 + srow) * K + cg;          // ks=0
    const bf16_t* gA1 = gA0 + QKV_E;                                // ks=1
    const bf16_t* gB  = Woc + (long)(n0 + srow) * K + cg;
    bf16_t* lA = As + tid * 8;
    bf16_t* lB = Bs + tid * 8;

    f32x4 acc[4][4] = {};

    for (int s = 0; s < K / 64; s++) {
        const int k0 = s * 64;
#pragma unroll
        for (int rr = 0; rr < 4; rr++) {
            const bf16x8 a0 = *(const bf16x8*)(gA0 + (long)rr * 32 * K + k0);
            const bf16x8 a1 = *(const bf16x8*)(gA1 + (long)rr * 32 * K + k0);
            bf16x8 sm;
#pragma unroll
            for (int e = 0; e < 8; e++)
                sm[e] = (bf16_t)((float)a0[e] + (float)a1[e]);
            *(bf16x8*)(lA + rr * 2048) = sm;
            load16_lds(gB + (long)rr * 32 * K + k0, lB + rr * 2048);
        }
        __syncthreads();
#pragma unroll
        for (int kh = 0; kh < 2; kh++) {
            bf16x8 af[4], bfr[4];
#pragma unroll
            for (int i = 0; i < 4; i++) {
                const int row = wr * 64 + i * 16 + r16;
                af[i] = *(const bf16x8*)(As + row * 64 +
                        (((kh << 2) + quad) ^ (row & 7)) * 8);
            }
#pragma unroll
            for (int j = 0; j < 4; j++) {
                const int row = wc * 64 + j * 16 + r16;
                bfr[j] = *(const bf16x8*)(Bs + row * 64 +
                        (((kh << 2) + quad) ^ (row & 7)) * 8);
            }
#pragma unroll
            for (int i = 0; i < 4; i++)
#pragma unroll
                for (int j = 0; j < 4; j++)
                    acc[i][j] = __builtin_amdgcn_mfma_f32_16x16x32_bf16(
                        af[i], bfr[j], acc[i][j], 0, 0, 0);
        }
        __syncthreads();
    }

#pragma unroll
    for (int i = 0; i < 4; i++)
#pragma unroll
        for (int j = 0; j < 4; j++) {
            const int gn = n0 + wc * 64 + j * 16 + r16;
            const float bval = bo[gn];
#pragma unroll
            for (int reg = 0; reg < 4; reg++) {
                const int gm = m0 + wr * 64 + i * 16 + quad * 4 + reg;
                C[(long)gm * N + gn] = acc[i][j][reg] + bval;
            }
        }
}

// ---------------------------------------------------------------------------
// k_init: zero the barrier counters (workspace is re-poisoned every iter).
// ---------------------------------------------------------------------------
__global__ __launch_bounds__(256) void k_init(unsigned* bar)
{
    if (threadIdx.x < 128) bar[threadIdx.x] = 0u;
}

// ---------------------------------------------------------------------------
// Persistent mega-kernel: all 5 stages, software grid barriers between.
// ---------------------------------------------------------------------------
__global__ __launch_bounds__(256, 2) void mega(
    const float* __restrict__ x, const float* __restrict__ mask,
    const float* __restrict__ Wq, const float* __restrict__ bq,
    const float* __restrict__ Wk, const float* __restrict__ bk,
    const float* __restrict__ Wv, const float* __restrict__ bv,
    const float* __restrict__ Wo, const float* __restrict__ bo,
    float* __restrict__ outp,
    bf16_t* Xc, bf16_t* Q, bf16_t* Kp, bf16_t* VT,
    bf16_t* SC, bf16_t* part, float* rowsum, unsigned* bar)
{
    __shared__ char smem[32768];
    const int tid = threadIdx.x;
    const int bid = blockIdx.x;
    const long gtid = (long)bid * NT_ + tid;

    const bf16_t* Wqc = Xc + QKV_E;
    const bf16_t* Wkc = Wqc + W_E;
    const bf16_t* Wvc = Wkc + W_E;
    const bf16_t* Woc = Wvc + W_E;

    // S1: cvt + rowsum zero
    for (long u = gtid; u < CVT_UNITS; u += (long)GRID_ * NT_)
        dev_cvt(u, x, Wq, Wk, Wv, Wo, Xc);
    if (gtid < BS_ / 4) {
        const float4 z = {0.f, 0.f, 0.f, 0.f};
        *(float4*)(rowsum + gtid * 4) = z;
    }
    gbar(bar, 0);

    // S2: QKV + V^T projections (768 tiles)
    for (int t = bid; t < 768; t += GRID_)
        dev_qkv_tile(t, Xc, Wqc, Wkc, Wvc, bq, bk, bv, Q, Kp, VT, smem, tid);
    gbar(bar, 1);

    // S3: scores (2048 tiles)
    for (int t = bid; t < 2048; t += GRID_)
        dev_scores_tile(t, Q, Kp, mask, SC, rowsum, smem, tid);
    gbar(bar, 2);

    // S4: PV split-K (512 tiles)
    for (int t = bid; t < 512; t += GRID_)
        dev_pv_tile(t, VT, SC, rowsum, part, smem, tid);
    gbar(bar, 3);

    // S5: out projection (256 tiles)
    for (int t = bid; t < 256; t += GRID_)
        dev_out_tile(t, part, Woc, bo, outp, smem, tid);
}

// ---------------------------------------------------------------------------
extern "C" void kernel_launch(void* const* d_in, const int* in_sizes, int n_in,
                              void* d_out, int out_size, void* d_ws, size_t ws_size,
                              hipStream_t stream)
{
    const float* x    = (const float*)d_in[0];
    const float* mask = (const float*)d_in[1];
    const float* Wq   = (const float*)d_in[2];
    const float* bq   = (const float*)d_in[3];
    const float* Wk   = (const float*)d_in[4];
    const float* bk   = (const float*)d_in[5];
    const float* Wv   = (const float*)d_in[6];
    const float* bv   = (const float*)d_in[7];
    const float* Wo   = (const float*)d_in[8];
    const float* bo   = (const float*)d_in[9];
    float* outp = (float*)d_out;

    char* ws = (char*)d_ws;
    bf16_t* SC = (bf16_t*)ws;   ws += (long)BS_ * S_ * 2;          // 64 MiB
    bf16_t* VT = (bf16_t*)ws;   ws += QKV_E * 2;                   // 8
    bf16_t* Q  = (bf16_t*)ws;   ws += QKV_E * 2;                   // 8
    bf16_t* Kp = (bf16_t*)ws;   ws += QKV_E * 2;                   // 8
    bf16_t* Xc = (bf16_t*)ws;   ws += (QKV_E + 4 * W_E) * 2;       // 10 (Xc|Wq|Wk|Wv|Wo)
    bf16_t* part = (bf16_t*)ws; ws += 2 * QKV_E * 2;               // 16 (KS=2)
    float* rowsum = (float*)ws; ws += (long)BS_ * 4;               // 32 KB
    unsigned* bar = (unsigned*)ws;                                 // 512 B

    dim3 blk(NT_);
    k_init<<<dim3(1), blk, 0, stream>>>(bar);
    mega<<<dim3(GRID_), blk, 0, stream>>>(
        x, mask, Wq, bq, Wk, bk, Wv, bv, Wo, bo, outp,
        Xc, Q, Kp, VT, SC, part, rowsum, bar);
}

// Round 7
// 625.295 us; speedup vs baseline: 1.1849x; 1.1849x over previous
//
#include <hip/hip_runtime.h>
#include <hip/hip_bf16.h>
#include <math.h>

typedef __bf16 bf16_t;
typedef __attribute__((ext_vector_type(8))) __bf16 bf16x8;
typedef __attribute__((ext_vector_type(4))) float f32x4;

constexpr int B_ = 2, S_ = 4096, D_ = 512;
constexpr int BS_ = B_ * S_;
constexpr int GRID_ = 512;                       // == 2 blocks/CU exactly
constexpr int NT_ = 256;
constexpr long QKV_E  = (long)BS_ * D_;          // 4 Mi elems
constexpr long W_E    = (long)D_ * D_;           // 256 Ki elems (2^18)
constexpr long CVT_UNITS = (QKV_E + 4 * W_E) / 4;    // 1,310,720
constexpr float SCALE_ = 0.044194173824159216f;      // 1/sqrt(512)

// Async global->LDS 16B copy. LDS dest must be wave-uniform base + lane*16.
__device__ __forceinline__ void load16_lds(const bf16_t* g, bf16_t* l) {
    __builtin_amdgcn_global_load_lds(
        (const __attribute__((address_space(1))) void*)g,
        (__attribute__((address_space(3))) void*)l, 16, 0, 0);
}

// ---------------------------------------------------------------------------
// Software grid barrier. Requires all GRID_ blocks co-resident
// (__launch_bounds__(256,2), 32KB LDS -> 2 blocks/CU * 256 CU = 512).
//
// Arrive: release fence (L2 wb) + agent-scope fetch_add (serializes at the
// device coherence point; accumulation across XCDs verified in round 5).
// Poll: atomic fetch_add(+0) RMW. RMWs on one address serialize at the SAME
// coherence point, so a poll can NEVER read a stale local-L2 copy.
//   - round 5 (ACQUIRE load poll): correct but per-poll buffer_inv storm
//     flushed every XCD L2 continuously -> 2.5x regression.
//   - round 6 (RELAXED load poll): serviced from stale local L2, never saw
//     remote arrivals -> infinite spin -> timeout.
//   - RMW(+0) poll: exact value, no cache side effects. s_sleep(32) thins
//     the serialization queue.
// One __threadfence() after the spin is the single acquire (one L2 inv).
// Guard 2^16 (~70ms/barrier): failure = wrong answer, never a hang.
// ---------------------------------------------------------------------------
__device__ __forceinline__ void gbar(unsigned* bar, int idx) {
    __syncthreads();                 // all waves done; vmcnt drained by barrier
    if (threadIdx.x == 0) {
        unsigned* c = bar + idx * 32;            // own 128B line per barrier
        __threadfence();                         // device-scope release (L2 wb)
        __hip_atomic_fetch_add(c, 1u, __ATOMIC_RELEASE, __HIP_MEMORY_SCOPE_AGENT);
        long guard = 0;
        while (__hip_atomic_fetch_add(c, 0u, __ATOMIC_RELAXED,
                                      __HIP_MEMORY_SCOPE_AGENT)
               < (unsigned)GRID_) {
            if (++guard > (1L << 16)) break;     // ~70ms safety valve
            __builtin_amdgcn_s_sleep(32);        // ~0.85us between polls
        }
        __threadfence();                         // acquire side (one L2 inv)
    }
    __syncthreads();
}

// ---------------------------------------------------------------------------
// Streaming: fp32->bf16 of x + 4 weights into contiguous Xc|Wq|Wk|Wv|Wo.
// ---------------------------------------------------------------------------
__device__ __forceinline__ void dev_cvt(long u,
    const float* x, const float* Wq, const float* Wk, const float* Wv,
    const float* Wo, bf16_t* dst)
{
    const long i = u * 4;
    const float* src; long o;
    if (i < QKV_E) { src = x; o = i; }
    else {
        const long j = i - QKV_E;
        const int w = (int)(j >> 18);
        o = j & (W_E - 1);
        src = (w == 0) ? Wq : (w == 1) ? Wk : (w == 2) ? Wv : Wo;
    }
    const float4 v = *(const float4*)(src + o);
    bf16_t out[4] = {(bf16_t)v.x, (bf16_t)v.y, (bf16_t)v.z, (bf16_t)v.w};
    *(uint2*)(dst + i) = *(uint2*)out;
}

// ---------------------------------------------------------------------------
// 128x128 tile GEMM K-loop, BK=64. LDS [128 rows][64 cols] bf16 per matrix.
// Linear gload_lds dest; XOR swizzle on the GLOBAL source col-group and on
// the read address (both-sides, rule 21). b128 reads at structural minimum.
// ---------------------------------------------------------------------------
__device__ __forceinline__ void kloop64(
    const bf16_t* At, const bf16_t* Bt, long ldA, long ldB, int kSteps,
    bf16_t* As, bf16_t* Bs, int tid, int wr, int wc, int quad, int r16,
    f32x4 (&acc)[4][4])
{
    const int srow = tid >> 3;                        // 0..31
    const int cg = ((tid & 7) ^ (srow & 7)) * 8;      // pre-swizzled src col
    const bf16_t* gA = At + (long)srow * ldA + cg;
    const bf16_t* gB = Bt + (long)srow * ldB + cg;
    bf16_t* lA = As + tid * 8;
    bf16_t* lB = Bs + tid * 8;

    for (int s = 0; s < kSteps; s++) {
        const int k0 = s * 64;
#pragma unroll
        for (int rr = 0; rr < 4; rr++) {
            load16_lds(gA + (long)rr * 32 * ldA + k0, lA + rr * 2048);
            load16_lds(gB + (long)rr * 32 * ldB + k0, lB + rr * 2048);
        }
        __syncthreads();
#pragma unroll
        for (int kh = 0; kh < 2; kh++) {
            bf16x8 af[4], bfr[4];
#pragma unroll
            for (int i = 0; i < 4; i++) {
                const int row = wr * 64 + i * 16 + r16;
                af[i] = *(const bf16x8*)(As + row * 64 +
                        (((kh << 2) + quad) ^ (row & 7)) * 8);
            }
#pragma unroll
            for (int j = 0; j < 4; j++) {
                const int row = wc * 64 + j * 16 + r16;
                bfr[j] = *(const bf16x8*)(Bs + row * 64 +
                        (((kh << 2) + quad) ^ (row & 7)) * 8);
            }
#pragma unroll
            for (int i = 0; i < 4; i++)
#pragma unroll
                for (int j = 0; j < 4; j++)
                    acc[i][j] = __builtin_amdgcn_mfma_f32_16x16x32_bf16(
                        af[i], bfr[j], acc[i][j], 0, 0, 0);
        }
        __syncthreads();
    }
}

// ---------------------------------------------------------------------------
// QKV + direct-V^T projections (sel 2 swaps operands: C[d][s] = V^T).
// ---------------------------------------------------------------------------
__device__ __forceinline__ void dev_qkv_tile(int t,
    const bf16_t* Xc, const bf16_t* Wqc, const bf16_t* Wkc, const bf16_t* Wvc,
    const float* bq, const float* bk, const float* bv,
    bf16_t* Q, bf16_t* Kp, bf16_t* VT, char* smem, int tid)
{
    constexpr int K = 512;
    const int sel = t >> 8;          // 0:Q 1:K 2:VT
    const int tt  = t & 255;

    bf16_t* As = (bf16_t*)smem;
    bf16_t* Bs = As + 128 * 64;
    const int wave = tid >> 6, lane = tid & 63;
    const int quad = lane >> 4, r16 = lane & 15;
    const int wr = wave >> 1, wc = wave & 1;

    f32x4 acc[4][4] = {};

    if (sel < 2) {
        const int m0 = (tt >> 2) * 128;          // X row tile (8192)
        const int n0 = (tt & 3) * 128;           // out-feature tile (512)
        const bf16_t* Bw = sel ? Wkc : Wqc;
        const float* bias = sel ? bk : bq;
        bf16_t* C = sel ? Kp : Q;
        kloop64(Xc + (long)m0 * K, Bw + (long)n0 * K, K, K, K / 64,
                As, Bs, tid, wr, wc, quad, r16, acc);
#pragma unroll
        for (int i = 0; i < 4; i++)
#pragma unroll
            for (int j = 0; j < 4; j++) {
                const int gn = n0 + wc * 64 + j * 16 + r16;
                const float bval = bias[gn];
#pragma unroll
                for (int reg = 0; reg < 4; reg++) {
                    const int gm = m0 + wr * 64 + i * 16 + quad * 4 + reg;
                    C[(long)gm * 512 + gn] = (bf16_t)(acc[i][j][reg] + bval);
                }
            }
    } else {
        const int m0 = (tt & 3) * 128;           // d tile (512)
        const int n0 = (tt >> 2) * 128;          // X row tile (8192)
        kloop64(Wvc + (long)m0 * K, Xc + (long)n0 * K, K, K, K / 64,
                As, Bs, tid, wr, wc, quad, r16, acc);
#pragma unroll
        for (int i = 0; i < 4; i++)
#pragma unroll
            for (int j = 0; j < 4; j++) {
                const int gn = n0 + wc * 64 + j * 16 + r16;   // global s-index
                const int b = gn >> 12, q = gn & 4095;
#pragma unroll
                for (int reg = 0; reg < 4; reg++) {
                    const int gm = m0 + wr * 64 + i * 16 + quad * 4 + reg; // d
                    VT[(long)b * D_ * S_ + (long)gm * S_ + q] =
                        (bf16_t)(acc[i][j][reg] + bv[gm]);
                }
            }
    }
}

// ---------------------------------------------------------------------------
// Scores: SC[q][k] = keep ? exp(scale*(Q.K)) : 0 (bf16), rowsum atomics.
// fp32 mask read directly (no pack pass). wlds padded [16][68].
// ---------------------------------------------------------------------------
__device__ __forceinline__ void dev_scores_tile(int t,
    const bf16_t* Q, const bf16_t* Kp, const float* mask,
    bf16_t* SC, float* rowsum, char* smem, int tid)
{
    constexpr int S = S_, K = D_;
    const int x = t & 31;
    const int y = (t >> 5) & 31;
    const int b = t >> 10;
    const int m0 = y * 128, n0 = x * 128;

    bf16_t* As = (bf16_t*)smem;
    bf16_t* Bs = As + 128 * 64;
    const int wave = tid >> 6, lane = tid & 63;
    const int quad = lane >> 4, r16 = lane & 15;
    const int wr = wave >> 1, wc = wave & 1;

    f32x4 acc[4][4] = {};
    kloop64(Q + (long)b * S * K + (long)m0 * K,
            Kp + (long)b * S * K + (long)n0 * K, K, K, K / 64,
            As, Bs, tid, wr, wc, quad, r16, acc);

    float* wlds = (float*)smem + wave * 1088;   // 16 rows x 68 cols fp32 (pad)
    const int erow = lane >> 2;
    const int ecg  = lane & 3;
    const long mbase = (long)b * S * S;

#pragma unroll
    for (int i = 0; i < 4; i++) {
#pragma unroll
        for (int j = 0; j < 4; j++)
#pragma unroll
            for (int reg = 0; reg < 4; reg++)
                wlds[(quad * 4 + reg) * 68 + j * 16 + r16] = acc[i][j][reg];
        __syncthreads();

        float v[16];
#pragma unroll
        for (int c = 0; c < 4; c++) {
            const float4 tv = *(const float4*)(wlds + erow * 68 + ecg * 16 + c * 4);
            v[c * 4 + 0] = tv.x; v[c * 4 + 1] = tv.y;
            v[c * 4 + 2] = tv.z; v[c * 4 + 3] = tv.w;
        }

        const int gm = m0 + wr * 64 + i * 16 + erow;
        const int gn = n0 + wc * 64 + ecg * 16;

        const float* mp = mask + mbase + (long)gm * S + gn;
        float e[16];
#pragma unroll
        for (int c = 0; c < 4; c++) {
            const float4 mk = *(const float4*)(mp + c * 4);
            e[c * 4 + 0] = (mk.x > 0.95f) ? __expf(v[c * 4 + 0] * SCALE_) : 0.f;
            e[c * 4 + 1] = (mk.y > 0.95f) ? __expf(v[c * 4 + 1] * SCALE_) : 0.f;
            e[c * 4 + 2] = (mk.z > 0.95f) ? __expf(v[c * 4 + 2] * SCALE_) : 0.f;
            e[c * 4 + 3] = (mk.w > 0.95f) ? __expf(v[c * 4 + 3] * SCALE_) : 0.f;
        }

        bf16x8 o0, o1;
        float rsum = 0.f;
#pragma unroll
        for (int tt = 0; tt < 8; tt++) {
            rsum += e[tt] + e[tt + 8];
            o0[tt] = (bf16_t)e[tt];
            o1[tt] = (bf16_t)e[tt + 8];
        }
        bf16_t* cp = SC + mbase + (long)gm * S + gn;
        *(bf16x8*)cp       = o0;
        *(bf16x8*)(cp + 8) = o1;

        rsum += __shfl_xor(rsum, 1, 64);
        rsum += __shfl_xor(rsum, 2, 64);
        if (ecg == 0) atomicAdd(&rowsum[b * S + gm], rsum);
        __syncthreads();
    }
}

// ---------------------------------------------------------------------------
// PV split-K (KS=2), normalized bf16 partials [ks][b][d][q].
// ---------------------------------------------------------------------------
__device__ __forceinline__ void dev_pv_tile(int t,
    const bf16_t* VT, const bf16_t* SC, const float* rowsum,
    bf16_t* part, char* smem, int tid)
{
    constexpr int S = S_, D = D_;
    constexpr int KC = S / 2;                   // 2048
    const int x = t & 31;                       // q tile
    const int y = (t >> 5) & 3;                 // d tile
    const int z = t >> 7;                       // 0..3
    const int b = z >> 1, ks = z & 1;
    const int m0 = y * 128, n0 = x * 128;
    const int kbeg = ks * KC;

    bf16_t* As = (bf16_t*)smem;
    bf16_t* Bs = As + 128 * 64;
    const int wave = tid >> 6, lane = tid & 63;
    const int quad = lane >> 4, r16 = lane & 15;
    const int wr = wave >> 1, wc = wave & 1;

    f32x4 acc[4][4] = {};
    kloop64(VT + (long)b * D * S + (long)m0 * S + kbeg,
            SC + (long)b * S * S + (long)n0 * S + kbeg, S, S, KC / 64,
            As, Bs, tid, wr, wc, quad, r16, acc);

    const long obase = ((long)ks * B_ + b) * (long)D * S;
#pragma unroll
    for (int i = 0; i < 4; i++)
#pragma unroll
        for (int j = 0; j < 4; j++) {
            const int gn = n0 + wc * 64 + j * 16 + r16;
            const float inv = 1.f / rowsum[b * S + gn];
#pragma unroll
            for (int reg = 0; reg < 4; reg++) {
                const int gm = m0 + wr * 64 + i * 16 + quad * 4 + reg;
                part[obase + (long)gm * S + gn] = (bf16_t)(acc[i][j][reg] * inv);
            }
        }
}

// ---------------------------------------------------------------------------
// Out projection with INLINE partial reduction (A = part0 + part1 reg-staged,
// swizzled ds_write; B = Wo via gload_lds). fp32 out + bias.
// ---------------------------------------------------------------------------
__device__ __forceinline__ void dev_out_tile(int t,
    const bf16_t* part, const bf16_t* Woc, const float* bo, float* C,
    char* smem, int tid)
{
    constexpr int N = 512, K = 512;
    const int m0 = (t >> 2) * 128, n0 = (t & 3) * 128;

    bf16_t* As = (bf16_t*)smem;
    bf16_t* Bs = As + 128 * 64;
    const int wave = tid >> 6, lane = tid & 63;
    const int quad = lane >> 4, r16 = lane & 15;
    const int wr = wave >> 1, wc = wave & 1;

    const int srow = tid >> 3;
    const int cg = ((tid & 7) ^ (srow & 7)) * 8;
    const bf16_t* gA0 = part + (long)(m0 + srow) * K + cg;          // ks=0
    const bf16_t* gA1 = gA0 + QKV_E;                                // ks=1
    const bf16_t* gB  = Woc + (long)(n0 + srow) * K + cg;
    bf16_t* lA = As + tid * 8;
    bf16_t* lB = Bs + tid * 8;

    f32x4 acc[4][4] = {};

    for (int s = 0; s < K / 64; s++) {
        const int k0 = s * 64;
#pragma unroll
        for (int rr = 0; rr < 4; rr++) {
            const bf16x8 a0 = *(const bf16x8*)(gA0 + (long)rr * 32 * K + k0);
            const bf16x8 a1 = *(const bf16x8*)(gA1 + (long)rr * 32 * K + k0);
            bf16x8 sm;
#pragma unroll
            for (int e = 0; e < 8; e++)
                sm[e] = (bf16_t)((float)a0[e] + (float)a1[e]);
            *(bf16x8*)(lA + rr * 2048) = sm;
            load16_lds(gB + (long)rr * 32 * K + k0, lB + rr * 2048);
        }
        __syncthreads();
#pragma unroll
        for (int kh = 0; kh < 2; kh++) {
            bf16x8 af[4], bfr[4];
#pragma unroll
            for (int i = 0; i < 4; i++) {
                const int row = wr * 64 + i * 16 + r16;
                af[i] = *(const bf16x8*)(As + row * 64 +
                        (((kh << 2) + quad) ^ (row & 7)) * 8);
            }
#pragma unroll
            for (int j = 0; j < 4; j++) {
                const int row = wc * 64 + j * 16 + r16;
                bfr[j] = *(const bf16x8*)(Bs + row * 64 +
                        (((kh << 2) + quad) ^ (row & 7)) * 8);
            }
#pragma unroll
            for (int i = 0; i < 4; i++)
#pragma unroll
                for (int j = 0; j < 4; j++)
                    acc[i][j] = __builtin_amdgcn_mfma_f32_16x16x32_bf16(
                        af[i], bfr[j], acc[i][j], 0, 0, 0);
        }
        __syncthreads();
    }

#pragma unroll
    for (int i = 0; i < 4; i++)
#pragma unroll
        for (int j = 0; j < 4; j++) {
            const int gn = n0 + wc * 64 + j * 16 + r16;
            const float bval = bo[gn];
#pragma unroll
            for (int reg = 0; reg < 4; reg++) {
                const int gm = m0 + wr * 64 + i * 16 + quad * 4 + reg;
                C[(long)gm * N + gn] = acc[i][j][reg] + bval;
            }
        }
}

// ---------------------------------------------------------------------------
// k_init: zero the barrier counters (workspace is re-poisoned every iter).
// ---------------------------------------------------------------------------
__global__ __launch_bounds__(256) void k_init(unsigned* bar)
{
    if (threadIdx.x < 128) bar[threadIdx.x] = 0u;
}

// ---------------------------------------------------------------------------
// Persistent mega-kernel: all 5 stages, software grid barriers between.
// ---------------------------------------------------------------------------
__global__ __launch_bounds__(256, 2) void mega(
    const float* __restrict__ x, const float* __restrict__ mask,
    const float* __restrict__ Wq, const float* __restrict__ bq,
    const float* __restrict__ Wk, const float* __restrict__ bk,
    const float* __restrict__ Wv, const float* __restrict__ bv,
    const float* __restrict__ Wo, const float* __restrict__ bo,
    float* __restrict__ outp,
    bf16_t* Xc, bf16_t* Q, bf16_t* Kp, bf16_t* VT,
    bf16_t* SC, bf16_t* part, float* rowsum, unsigned* bar)
{
    __shared__ char smem[32768];
    const int tid = threadIdx.x;
    const int bid = blockIdx.x;
    const long gtid = (long)bid * NT_ + tid;

    const bf16_t* Wqc = Xc + QKV_E;
    const bf16_t* Wkc = Wqc + W_E;
    const bf16_t* Wvc = Wkc + W_E;
    const bf16_t* Woc = Wvc + W_E;

    // S1: cvt + rowsum zero
    for (long u = gtid; u < CVT_UNITS; u += (long)GRID_ * NT_)
        dev_cvt(u, x, Wq, Wk, Wv, Wo, Xc);
    if (gtid < BS_ / 4) {
        const float4 z = {0.f, 0.f, 0.f, 0.f};
        *(float4*)(rowsum + gtid * 4) = z;
    }
    gbar(bar, 0);

    // S2: QKV + V^T projections (768 tiles)
    for (int t = bid; t < 768; t += GRID_)
        dev_qkv_tile(t, Xc, Wqc, Wkc, Wvc, bq, bk, bv, Q, Kp, VT, smem, tid);
    gbar(bar, 1);

    // S3: scores (2048 tiles)
    for (int t = bid; t < 2048; t += GRID_)
        dev_scores_tile(t, Q, Kp, mask, SC, rowsum, smem, tid);
    gbar(bar, 2);

    // S4: PV split-K (512 tiles)
    for (int t = bid; t < 512; t += GRID_)
        dev_pv_tile(t, VT, SC, rowsum, part, smem, tid);
    gbar(bar, 3);

    // S5: out projection (256 tiles)
    for (int t = bid; t < 256; t += GRID_)
        dev_out_tile(t, part, Woc, bo, outp, smem, tid);
}

// ---------------------------------------------------------------------------
extern "C" void kernel_launch(void* const* d_in, const int* in_sizes, int n_in,
                              void* d_out, int out_size, void* d_ws, size_t ws_size,
                              hipStream_t stream)
{
    const float* x    = (const float*)d_in[0];
    const float* mask = (const float*)d_in[1];
    const float* Wq   = (const float*)d_in[2];
    const float* bq   = (const float*)d_in[3];
    const float* Wk   = (const float*)d_in[4];
    const float* bk   = (const float*)d_in[5];
    const float* Wv   = (const float*)d_in[6];
    const float* bv   = (const float*)d_in[7];
    const float* Wo   = (const float*)d_in[8];
    const float* bo   = (const float*)d_in[9];
    float* outp = (float*)d_out;

    char* ws = (char*)d_ws;
    bf16_t* SC = (bf16_t*)ws;   ws += (long)BS_ * S_ * 2;          // 64 MiB
    bf16_t* VT = (bf16_t*)ws;   ws += QKV_E * 2;                   // 8
    bf16_t* Q  = (bf16_t*)ws;   ws += QKV_E * 2;                   // 8
    bf16_t* Kp = (bf16_t*)ws;   ws += QKV_E * 2;                   // 8
    bf16_t* Xc = (bf16_t*)ws;   ws += (QKV_E + 4 * W_E) * 2;       // 10 (Xc|Wq|Wk|Wv|Wo)
    bf16_t* part = (bf16_t*)ws; ws += 2 * QKV_E * 2;               // 16 (KS=2)
    float* rowsum = (float*)ws; ws += (long)BS_ * 4;               // 32 KB
    unsigned* bar = (unsigned*)ws;                                 // 512 B

    dim3 blk(NT_);
    k_init<<<dim3(1), blk, 0, stream>>>(bar);
    mega<<<dim3(GRID_), blk, 0, stream>>>(
        x, mask, Wq, bq, Wk, bk, Wv, bv, Wo, bo, outp,
        Xc, Q, Kp, VT, SC, part, rowsum, bar);
}

// Round 8
// 353.760 us; speedup vs baseline: 2.0944x; 1.7676x over previous
//
#include <hip/hip_runtime.h>
#include <hip/hip_bf16.h>
#include <math.h>

typedef __bf16 bf16_t;
typedef __attribute__((ext_vector_type(8))) __bf16 bf16x8;
typedef __attribute__((ext_vector_type(4))) float f32x4;

constexpr int B_ = 2, S_ = 4096, D_ = 512;
constexpr int BS_ = B_ * S_;
constexpr int NT_ = 256;
constexpr long QKV_E  = (long)BS_ * D_;          // 4 Mi elems
constexpr long W_E    = (long)D_ * D_;           // 256 Ki elems (2^18)
constexpr long CVT_UNITS = (QKV_E + 4 * W_E) / 4;    // 1,310,720
constexpr float SCALE_ = 0.044194173824159216f;      // 1/sqrt(512)

// Async global->LDS 16B copy. LDS dest must be wave-uniform base + lane*16.
__device__ __forceinline__ void load16_lds(const bf16_t* g, bf16_t* l) {
    __builtin_amdgcn_global_load_lds(
        (const __attribute__((address_space(1))) void*)g,
        (__attribute__((address_space(3))) void*)l, 16, 0, 0);
}

// Bijective XCD swizzle (nwg % 8 == 0): each XCD gets a CONTIGUOUS chunk of
// the tile space -> neighboring tiles (sharing operand panels) hit one L2.
__device__ __forceinline__ int swz8(int bid, int chunk) {
    return (bid & 7) * chunk + (bid >> 3);
}

// ---------------------------------------------------------------------------
// Streaming: fp32->bf16 of x + 4 weights into contiguous Xc|Wq|Wk|Wv|Wo.
// ---------------------------------------------------------------------------
__device__ __forceinline__ void dev_cvt(long u,
    const float* x, const float* Wq, const float* Wk, const float* Wv,
    const float* Wo, bf16_t* dst)
{
    const long i = u * 4;
    const float* src; long o;
    if (i < QKV_E) { src = x; o = i; }
    else {
        const long j = i - QKV_E;
        const int w = (int)(j >> 18);
        o = j & (W_E - 1);
        src = (w == 0) ? Wq : (w == 1) ? Wk : (w == 2) ? Wv : Wo;
    }
    const float4 v = *(const float4*)(src + o);
    bf16_t out[4] = {(bf16_t)v.x, (bf16_t)v.y, (bf16_t)v.z, (bf16_t)v.w};
    *(uint2*)(dst + i) = *(uint2*)out;
}

// ---------------------------------------------------------------------------
// 128x128 tile GEMM K-loop, BK=64. LDS [128 rows][64 cols] bf16 per matrix.
// Linear gload_lds dest; XOR swizzle on the GLOBAL source col-group and on
// the read address (both-sides, rule 21). b128 reads at structural minimum.
// ---------------------------------------------------------------------------
__device__ __forceinline__ void kloop64(
    const bf16_t* At, const bf16_t* Bt, long ldA, long ldB, int kSteps,
    bf16_t* As, bf16_t* Bs, int tid, int wr, int wc, int quad, int r16,
    f32x4 (&acc)[4][4])
{
    const int srow = tid >> 3;                        // 0..31
    const int cg = ((tid & 7) ^ (srow & 7)) * 8;      // pre-swizzled src col
    const bf16_t* gA = At + (long)srow * ldA + cg;
    const bf16_t* gB = Bt + (long)srow * ldB + cg;
    bf16_t* lA = As + tid * 8;
    bf16_t* lB = Bs + tid * 8;

    for (int s = 0; s < kSteps; s++) {
        const int k0 = s * 64;
#pragma unroll
        for (int rr = 0; rr < 4; rr++) {
            load16_lds(gA + (long)rr * 32 * ldA + k0, lA + rr * 2048);
            load16_lds(gB + (long)rr * 32 * ldB + k0, lB + rr * 2048);
        }
        __syncthreads();
#pragma unroll
        for (int kh = 0; kh < 2; kh++) {
            bf16x8 af[4], bfr[4];
#pragma unroll
            for (int i = 0; i < 4; i++) {
                const int row = wr * 64 + i * 16 + r16;
                af[i] = *(const bf16x8*)(As + row * 64 +
                        (((kh << 2) + quad) ^ (row & 7)) * 8);
            }
#pragma unroll
            for (int j = 0; j < 4; j++) {
                const int row = wc * 64 + j * 16 + r16;
                bfr[j] = *(const bf16x8*)(Bs + row * 64 +
                        (((kh << 2) + quad) ^ (row & 7)) * 8);
            }
#pragma unroll
            for (int i = 0; i < 4; i++)
#pragma unroll
                for (int j = 0; j < 4; j++)
                    acc[i][j] = __builtin_amdgcn_mfma_f32_16x16x32_bf16(
                        af[i], bfr[j], acc[i][j], 0, 0, 0);
        }
        __syncthreads();
    }
}

// ---------------------------------------------------------------------------
// QKV + direct-V^T projections (sel 2 swaps operands: C[d][s] = V^T).
// ---------------------------------------------------------------------------
__device__ __forceinline__ void dev_qkv_tile(int t,
    const bf16_t* Xc, const bf16_t* Wqc, const bf16_t* Wkc, const bf16_t* Wvc,
    const float* bq, const float* bk, const float* bv,
    bf16_t* Q, bf16_t* Kp, bf16_t* VT, char* smem, int tid)
{
    constexpr int K = 512;
    const int sel = t >> 8;          // 0:Q 1:K 2:VT
    const int tt  = t & 255;

    bf16_t* As = (bf16_t*)smem;
    bf16_t* Bs = As + 128 * 64;
    const int wave = tid >> 6, lane = tid & 63;
    const int quad = lane >> 4, r16 = lane & 15;
    const int wr = wave >> 1, wc = wave & 1;

    f32x4 acc[4][4] = {};

    if (sel < 2) {
        const int m0 = (tt >> 2) * 128;          // X row tile (8192)
        const int n0 = (tt & 3) * 128;           // out-feature tile (512)
        const bf16_t* Bw = sel ? Wkc : Wqc;
        const float* bias = sel ? bk : bq;
        bf16_t* C = sel ? Kp : Q;
        kloop64(Xc + (long)m0 * K, Bw + (long)n0 * K, K, K, K / 64,
                As, Bs, tid, wr, wc, quad, r16, acc);
#pragma unroll
        for (int i = 0; i < 4; i++)
#pragma unroll
            for (int j = 0; j < 4; j++) {
                const int gn = n0 + wc * 64 + j * 16 + r16;
                const float bval = bias[gn];
#pragma unroll
                for (int reg = 0; reg < 4; reg++) {
                    const int gm = m0 + wr * 64 + i * 16 + quad * 4 + reg;
                    C[(long)gm * 512 + gn] = (bf16_t)(acc[i][j][reg] + bval);
                }
            }
    } else {
        const int m0 = (tt & 3) * 128;           // d tile (512)
        const int n0 = (tt >> 2) * 128;          // X row tile (8192)
        kloop64(Wvc + (long)m0 * K, Xc + (long)n0 * K, K, K, K / 64,
                As, Bs, tid, wr, wc, quad, r16, acc);
#pragma unroll
        for (int i = 0; i < 4; i++)
#pragma unroll
            for (int j = 0; j < 4; j++) {
                const int gn = n0 + wc * 64 + j * 16 + r16;   // global s-index
                const int b = gn >> 12, q = gn & 4095;
#pragma unroll
                for (int reg = 0; reg < 4; reg++) {
                    const int gm = m0 + wr * 64 + i * 16 + quad * 4 + reg; // d
                    VT[(long)b * D_ * S_ + (long)gm * S_ + q] =
                        (bf16_t)(acc[i][j][reg] + bv[gm]);
                }
            }
    }
}

// ---------------------------------------------------------------------------
// Scores: SC[q][k] = keep ? exp(scale*(Q.K)) : 0 (bf16), rowsum atomics.
// fp32 mask read directly (no pack pass). wlds padded [16][68].
// ---------------------------------------------------------------------------
__device__ __forceinline__ void dev_scores_tile(int t,
    const bf16_t* Q, const bf16_t* Kp, const float* mask,
    bf16_t* SC, float* rowsum, char* smem, int tid)
{
    constexpr int S = S_, K = D_;
    const int x = t & 31;
    const int y = (t >> 5) & 31;
    const int b = t >> 10;
    const int m0 = y * 128, n0 = x * 128;

    bf16_t* As = (bf16_t*)smem;
    bf16_t* Bs = As + 128 * 64;
    const int wave = tid >> 6, lane = tid & 63;
    const int quad = lane >> 4, r16 = lane & 15;
    const int wr = wave >> 1, wc = wave & 1;

    f32x4 acc[4][4] = {};
    kloop64(Q + (long)b * S * K + (long)m0 * K,
            Kp + (long)b * S * K + (long)n0 * K, K, K, K / 64,
            As, Bs, tid, wr, wc, quad, r16, acc);

    float* wlds = (float*)smem + wave * 1088;   // 16 rows x 68 cols fp32 (pad)
    const int erow = lane >> 2;
    const int ecg  = lane & 3;
    const long mbase = (long)b * S * S;

#pragma unroll
    for (int i = 0; i < 4; i++) {
#pragma unroll
        for (int j = 0; j < 4; j++)
#pragma unroll
            for (int reg = 0; reg < 4; reg++)
                wlds[(quad * 4 + reg) * 68 + j * 16 + r16] = acc[i][j][reg];
        __syncthreads();

        float v[16];
#pragma unroll
        for (int c = 0; c < 4; c++) {
            const float4 tv = *(const float4*)(wlds + erow * 68 + ecg * 16 + c * 4);
            v[c * 4 + 0] = tv.x; v[c * 4 + 1] = tv.y;
            v[c * 4 + 2] = tv.z; v[c * 4 + 3] = tv.w;
        }

        const int gm = m0 + wr * 64 + i * 16 + erow;
        const int gn = n0 + wc * 64 + ecg * 16;

        const float* mp = mask + mbase + (long)gm * S + gn;
        float e[16];
#pragma unroll
        for (int c = 0; c < 4; c++) {
            const float4 mk = *(const float4*)(mp + c * 4);
            e[c * 4 + 0] = (mk.x > 0.95f) ? __expf(v[c * 4 + 0] * SCALE_) : 0.f;
            e[c * 4 + 1] = (mk.y > 0.95f) ? __expf(v[c * 4 + 1] * SCALE_) : 0.f;
            e[c * 4 + 2] = (mk.z > 0.95f) ? __expf(v[c * 4 + 2] * SCALE_) : 0.f;
            e[c * 4 + 3] = (mk.w > 0.95f) ? __expf(v[c * 4 + 3] * SCALE_) : 0.f;
        }

        bf16x8 o0, o1;
        float rsum = 0.f;
#pragma unroll
        for (int tt = 0; tt < 8; tt++) {
            rsum += e[tt] + e[tt + 8];
            o0[tt] = (bf16_t)e[tt];
            o1[tt] = (bf16_t)e[tt + 8];
        }
        bf16_t* cp = SC + mbase + (long)gm * S + gn;
        *(bf16x8*)cp       = o0;
        *(bf16x8*)(cp + 8) = o1;

        rsum += __shfl_xor(rsum, 1, 64);
        rsum += __shfl_xor(rsum, 2, 64);
        if (ecg == 0) atomicAdd(&rowsum[b * S + gm], rsum);
        __syncthreads();
    }
}

// ---------------------------------------------------------------------------
// PV split-K (KS=4), normalized bf16 partials [ks][b][d][q].
// ---------------------------------------------------------------------------
__device__ __forceinline__ void dev_pv_tile(int t,
    const bf16_t* VT, const bf16_t* SC, const float* rowsum,
    bf16_t* part, char* smem, int tid)
{
    constexpr int S = S_, D = D_;
    constexpr int KC = S / 4;                   // 1024
    const int x = t & 31;                       // q tile
    const int y = (t >> 5) & 3;                 // d tile
    const int z = t >> 7;                       // 0..7 = b*4+ks
    const int b = z >> 2, ks = z & 3;
    const int m0 = y * 128, n0 = x * 128;
    const int kbeg = ks * KC;

    bf16_t* As = (bf16_t*)smem;
    bf16_t* Bs = As + 128 * 64;
    const int wave = tid >> 6, lane = tid & 63;
    const int quad = lane >> 4, r16 = lane & 15;
    const int wr = wave >> 1, wc = wave & 1;

    f32x4 acc[4][4] = {};
    kloop64(VT + (long)b * D * S + (long)m0 * S + kbeg,
            SC + (long)b * S * S + (long)n0 * S + kbeg, S, S, KC / 64,
            As, Bs, tid, wr, wc, quad, r16, acc);

    const long obase = ((long)ks * B_ + b) * (long)D * S;
#pragma unroll
    for (int i = 0; i < 4; i++)
#pragma unroll
        for (int j = 0; j < 4; j++) {
            const int gn = n0 + wc * 64 + j * 16 + r16;
            const float inv = 1.f / rowsum[b * S + gn];
#pragma unroll
            for (int reg = 0; reg < 4; reg++) {
                const int gm = m0 + wr * 64 + i * 16 + quad * 4 + reg;
                part[obase + (long)gm * S + gn] = (bf16_t)(acc[i][j][reg] * inv);
            }
        }
}

// ---------------------------------------------------------------------------
// Out projection with INLINE 4-way partial reduction (A = sum of 4 normalized
// bf16 partials, reg-staged + swizzled ds_write; B = Wo via gload_lds).
// Reference view() trick: part's flat [ks][b*D*S] layout IS the reshaped
// [BS][D] A-matrix (torch .transpose(1,2).view(B,S,D) is a reinterpret).
// ---------------------------------------------------------------------------
__device__ __forceinline__ void dev_out_tile(int t,
    const bf16_t* part, const bf16_t* Woc, const float* bo, float* C,
    char* smem, int tid)
{
    constexpr int N = 512, K = 512;
    const int m0 = (t >> 2) * 128, n0 = (t & 3) * 128;

    bf16_t* As = (bf16_t*)smem;
    bf16_t* Bs = As + 128 * 64;
    const int wave = tid >> 6, lane = tid & 63;
    const int quad = lane >> 4, r16 = lane & 15;
    const int wr = wave >> 1, wc = wave & 1;

    const int srow = tid >> 3;
    const int cg = ((tid & 7) ^ (srow & 7)) * 8;
    const bf16_t* gA0 = part + (long)(m0 + srow) * K + cg;
    const bf16_t* gB  = Woc + (long)(n0 + srow) * K + cg;
    bf16_t* lA = As + tid * 8;
    bf16_t* lB = Bs + tid * 8;

    f32x4 acc[4][4] = {};

    for (int s = 0; s < K / 64; s++) {
        const int k0 = s * 64;
#pragma unroll
        for (int rr = 0; rr < 4; rr++) {
            const bf16x8 a0 = *(const bf16x8*)(gA0 + (long)rr * 32 * K + k0);
            const bf16x8 a1 = *(const bf16x8*)(gA0 + QKV_E + (long)rr * 32 * K + k0);
            const bf16x8 a2 = *(const bf16x8*)(gA0 + 2 * QKV_E + (long)rr * 32 * K + k0);
            const bf16x8 a3 = *(const bf16x8*)(gA0 + 3 * QKV_E + (long)rr * 32 * K + k0);
            bf16x8 sm;
#pragma unroll
            for (int e = 0; e < 8; e++)
                sm[e] = (bf16_t)((float)a0[e] + (float)a1[e] +
                                 (float)a2[e] + (float)a3[e]);
            *(bf16x8*)(lA + rr * 2048) = sm;
            load16_lds(gB + (long)rr * 32 * K + k0, lB + rr * 2048);
        }
        __syncthreads();
#pragma unroll
        for (int kh = 0; kh < 2; kh++) {
            bf16x8 af[4], bfr[4];
#pragma unroll
            for (int i = 0; i < 4; i++) {
                const int row = wr * 64 + i * 16 + r16;
                af[i] = *(const bf16x8*)(As + row * 64 +
                        (((kh << 2) + quad) ^ (row & 7)) * 8);
            }
#pragma unroll
            for (int j = 0; j < 4; j++) {
                const int row = wc * 64 + j * 16 + r16;
                bfr[j] = *(const bf16x8*)(Bs + row * 64 +
                        (((kh << 2) + quad) ^ (row & 7)) * 8);
            }
#pragma unroll
            for (int i = 0; i < 4; i++)
#pragma unroll
                for (int j = 0; j < 4; j++)
                    acc[i][j] = __builtin_amdgcn_mfma_f32_16x16x32_bf16(
                        af[i], bfr[j], acc[i][j], 0, 0, 0);
        }
        __syncthreads();
    }

#pragma unroll
    for (int i = 0; i < 4; i++)
#pragma unroll
        for (int j = 0; j < 4; j++) {
            const int gn = n0 + wc * 64 + j * 16 + r16;
            const float bval = bo[gn];
#pragma unroll
            for (int reg = 0; reg < 4; reg++) {
                const int gm = m0 + wr * 64 + i * 16 + quad * 4 + reg;
                C[(long)gm * N + gn] = acc[i][j][reg] + bval;
            }
        }
}

// ---------------------------------------------------------------------------
// 5 plain launches, ONE TILE PER BLOCK (full occupancy: 4 blocks/CU vs the
// round-4 grid=512 loop's 2/CU) + XCD-contiguous swizzle.
// ---------------------------------------------------------------------------
__global__ __launch_bounds__(256) void k_s1(
    const float* x, const float* mask, const float* Wq, const float* Wk,
    const float* Wv, const float* Wo, bf16_t* Xc, float* rowsum)
{
    const long gtid = (long)blockIdx.x * NT_ + threadIdx.x;
    for (long u = gtid; u < CVT_UNITS; u += 1280L * NT_)
        dev_cvt(u, x, Wq, Wk, Wv, Wo, Xc);
    if (gtid < BS_ / 4) {
        const float4 z = {0.f, 0.f, 0.f, 0.f};
        *(float4*)(rowsum + gtid * 4) = z;
    }
}

__global__ __launch_bounds__(256) void k_s2(
    const bf16_t* Xc, const float* bq, const float* bk, const float* bv,
    bf16_t* Q, bf16_t* Kp, bf16_t* VT)
{
    __shared__ char smem[32768];
    const bf16_t* Wqc = Xc + QKV_E;
    dev_qkv_tile(swz8(blockIdx.x, 96), Xc, Wqc, Wqc + W_E, Wqc + 2 * W_E,
                 bq, bk, bv, Q, Kp, VT, smem, threadIdx.x);
}

__global__ __launch_bounds__(256) void k_s3(
    const bf16_t* Q, const bf16_t* Kp, const float* mask,
    bf16_t* SC, float* rowsum)
{
    __shared__ char smem[32768];
    dev_scores_tile(swz8(blockIdx.x, 256), Q, Kp, mask, SC, rowsum,
                    smem, threadIdx.x);
}

__global__ __launch_bounds__(256) void k_s4(
    const bf16_t* VT, const bf16_t* SC, const float* rowsum, bf16_t* part)
{
    __shared__ char smem[32768];
    dev_pv_tile(swz8(blockIdx.x, 128), VT, SC, rowsum, part, smem, threadIdx.x);
}

__global__ __launch_bounds__(256) void k_s6(
    const bf16_t* part, const bf16_t* Xc, const float* bo, float* C)
{
    __shared__ char smem[32768];
    const bf16_t* Woc = Xc + QKV_E + 3 * W_E;
    dev_out_tile(swz8(blockIdx.x, 32), part, Woc, bo, C, smem, threadIdx.x);
}

// ---------------------------------------------------------------------------
extern "C" void kernel_launch(void* const* d_in, const int* in_sizes, int n_in,
                              void* d_out, int out_size, void* d_ws, size_t ws_size,
                              hipStream_t stream)
{
    const float* x    = (const float*)d_in[0];
    const float* mask = (const float*)d_in[1];
    const float* Wq   = (const float*)d_in[2];
    const float* bq   = (const float*)d_in[3];
    const float* Wk   = (const float*)d_in[4];
    const float* bk   = (const float*)d_in[5];
    const float* Wv   = (const float*)d_in[6];
    const float* bv   = (const float*)d_in[7];
    const float* Wo   = (const float*)d_in[8];
    const float* bo   = (const float*)d_in[9];
    float* outp = (float*)d_out;

    char* ws = (char*)d_ws;
    bf16_t* SC = (bf16_t*)ws;   ws += (long)BS_ * S_ * 2;          // 64 MiB
    bf16_t* VT = (bf16_t*)ws;   ws += QKV_E * 2;                   // 8
    bf16_t* Q  = (bf16_t*)ws;   ws += QKV_E * 2;                   // 8
    bf16_t* Kp = (bf16_t*)ws;   ws += QKV_E * 2;                   // 8
    bf16_t* Xc = (bf16_t*)ws;   ws += (QKV_E + 4 * W_E) * 2;       // 10 (Xc|Wq|Wk|Wv|Wo)
    bf16_t* part = (bf16_t*)ws; ws += 4 * QKV_E * 2;               // 32 (KS=4)
    float* rowsum = (float*)ws; ws += (long)BS_ * 4;               // 32 KB

    dim3 blk(NT_);
    k_s1<<<dim3(1280), blk, 0, stream>>>(x, mask, Wq, Wk, Wv, Wo, Xc, rowsum);
    k_s2<<<dim3(768),  blk, 0, stream>>>(Xc, bq, bk, bv, Q, Kp, VT);
    k_s3<<<dim3(2048), blk, 0, stream>>>(Q, Kp, mask, SC, rowsum);
    k_s4<<<dim3(1024), blk, 0, stream>>>(VT, SC, rowsum, part);
    k_s6<<<dim3(256),  blk, 0, stream>>>(part, Xc, bo, outp);
}